// Round 8
// baseline (802.555 us; speedup 1.0000x reference)
//
#include <hip/hip_runtime.h>
#include <hip/hip_cooperative_groups.h>

namespace cg = cooperative_groups;

#define GN_EPS 1e-5f

typedef float f32x4 __attribute__((ext_vector_type(4)));

// Problem constants (fixed by setup_inputs): N=131072, U=256, B=64
constexpr int U       = 256;                 // units (row = 1 KB = 64 lanes x 16 B)
constexpr int NPG     = 2048;                // nodes (rows) per graph
constexpr int NGRAPH  = 64;
constexpr int UF4     = U / 4;               // 64 float4 per row

constexpr int CH      = 32;                  // chunks per graph
constexpr int RPC     = NPG / CH;            // 64 rows per chunk
constexpr int BLK     = 256;                 // 4 waves
constexpr int WAVES   = BLK / 64;
constexpr int NBLK    = NGRAPH * CH;         // 2048 blocks = 8/CU co-resident
constexpr int A_ITERS = RPC / WAVES;         // 16 rows per wave (phase A)
constexpr int B_ITERS = RPC * UF4 / BLK;     // 16 float4 per thread (phase B)

// Workspace layout (floats), ~4.3 MB:
constexpr size_t WS_SUM  = 0;
constexpr size_t WS_SQ   = (size_t)NGRAPH * CH * U;
constexpr size_t WS_MEAN = WS_SQ + (size_t)NGRAPH * CH * U;
constexpr size_t WS_INV  = WS_MEAN + (size_t)NGRAPH * U;

// ================= fused cooperative kernel =================
__global__ __launch_bounds__(BLK, 8) void gn_fused(
    const float* __restrict__ x,
    const float* __restrict__ gamma,
    const float* __restrict__ beta,
    float* __restrict__ ws,
    float* __restrict__ out)
{
    const int bid  = blockIdx.x;
    const int c    = bid & (CH - 1);
    const int g    = bid / CH;
    const int t    = threadIdx.x;
    const int wave = t >> 6;
    const int lane = t & 63;

    // ---- Phase A: partial column sums over this block's 64 rows ----
    const size_t row0 = (size_t)g * NPG + (size_t)c * RPC + wave;
    const f32x4* xr = reinterpret_cast<const f32x4*>(x) + row0 * UF4 + lane;
    f32x4 s = (f32x4)0.f;
    f32x4 q = (f32x4)0.f;
#pragma unroll 8
    for (int i = 0; i < A_ITERS; ++i) {
        const f32x4 v = xr[(size_t)i * WAVES * UF4];
        s += v;
        q += v * v;
    }

    __shared__ f32x4 ssum[WAVES][64];
    __shared__ f32x4 ssq [WAVES][64];
    ssum[wave][lane] = s;
    ssq [wave][lane] = q;
    __syncthreads();

    if (t < 64) {
        f32x4 s2 = ssum[0][t];
        f32x4 q2 = ssq [0][t];
#pragma unroll
        for (int w = 1; w < WAVES; ++w) { s2 += ssum[w][t]; q2 += ssq[w][t]; }
        const size_t o = ((size_t)g * CH + c) * UF4 + t;
        reinterpret_cast<f32x4*>(ws + WS_SUM)[o] = s2;
        reinterpret_cast<f32x4*>(ws + WS_SQ )[o] = q2;
    }

    cg::this_grid().sync();

    // ---- Distributed finalize: this block owns units [c*8, c*8+8) of graph g ----
    {
        const int c2 = t & 31;               // chunk to read
        const int ul = t >> 5;               // 0..7 local unit
        const int u  = c * 8 + ul;
        float ps = ws[WS_SUM + ((size_t)g * CH + c2) * U + u];
        float pq = ws[WS_SQ  + ((size_t)g * CH + c2) * U + u];
#pragma unroll
        for (int m = 1; m < 32; m <<= 1) {
            ps += __shfl_xor(ps, m);
            pq += __shfl_xor(pq, m);
        }
        if (c2 == 0) {
            const float invn = 1.0f / (float)NPG;
            const float mean = ps * invn;
            const float var  = fmaxf(pq * invn - mean * mean, 0.f);
            ws[WS_MEAN + (size_t)g * U + u] = mean;
            ws[WS_INV  + (size_t)g * U + u] = 1.0f / (sqrtf(var) + GN_EPS);
        }
    }

    cg::this_grid().sync();

    // ---- Phase B: streaming normalize of this block's own 64 rows ----
    const int f4 = t & (UF4 - 1);            // loop-invariant float4 column
    const f32x4 m  = reinterpret_cast<const f32x4*>(ws + WS_MEAN + (size_t)g * U)[f4];
    const f32x4 iv = reinterpret_cast<const f32x4*>(ws + WS_INV  + (size_t)g * U)[f4];

    const size_t base = ((size_t)g * NPG + (size_t)c * RPC) * UF4;
    const f32x4* xv = reinterpret_cast<const f32x4*>(x)     + base;
    const f32x4* gv = reinterpret_cast<const f32x4*>(gamma) + base;
    const f32x4* bv = reinterpret_cast<const f32x4*>(beta)  + base;
    f32x4*       ov = reinterpret_cast<f32x4*>(out)         + base;

#pragma unroll 4
    for (int i = 0; i < B_ITERS; ++i) {
        const int idx = i * BLK + t;
        const f32x4 v  = xv[idx];                               // L3-hot from phase A
        const f32x4 g4 = __builtin_nontemporal_load(gv + idx);  // single-use streams
        const f32x4 b4 = __builtin_nontemporal_load(bv + idx);
        const f32x4 o  = g4 * ((v - m) * iv) + b4;
        __builtin_nontemporal_store(o, ov + idx);
    }
}

// ================= fallback 3-kernel path (proven, round 4/5) =================
__global__ __launch_bounds__(BLK) void gn_partial(
    const float* __restrict__ x, float* __restrict__ ws)
{
    const int c = blockIdx.x & (CH - 1);
    const int g = blockIdx.x / CH;
    const int t = threadIdx.x;
    const int wave = t >> 6, lane = t & 63;
    const size_t row0 = (size_t)g * NPG + (size_t)c * RPC + wave;
    const f32x4* xr = reinterpret_cast<const f32x4*>(x) + row0 * UF4 + lane;
    f32x4 s = (f32x4)0.f, q = (f32x4)0.f;
#pragma unroll 8
    for (int i = 0; i < A_ITERS; ++i) {
        const f32x4 v = xr[(size_t)i * WAVES * UF4];
        s += v; q += v * v;
    }
    __shared__ f32x4 ssum[WAVES][64];
    __shared__ f32x4 ssq [WAVES][64];
    ssum[wave][lane] = s; ssq[wave][lane] = q;
    __syncthreads();
    if (t < 64) {
        f32x4 s2 = ssum[0][t], q2 = ssq[0][t];
#pragma unroll
        for (int w = 1; w < WAVES; ++w) { s2 += ssum[w][t]; q2 += ssq[w][t]; }
        const size_t o = ((size_t)g * CH + c) * UF4 + t;
        reinterpret_cast<f32x4*>(ws + WS_SUM)[o] = s2;
        reinterpret_cast<f32x4*>(ws + WS_SQ )[o] = q2;
    }
}

__global__ __launch_bounds__(U) void gn_finalize(float* __restrict__ ws)
{
    const int g = blockIdx.x;
    const int t = threadIdx.x;
    const float* psum = ws + WS_SUM + (size_t)g * CH * U + t;
    const float* psq  = ws + WS_SQ  + (size_t)g * CH * U + t;
    float s = 0.f, q = 0.f;
#pragma unroll
    for (int c = 0; c < CH; ++c) { s += psum[(size_t)c * U]; q += psq[(size_t)c * U]; }
    const float invn = 1.0f / (float)NPG;
    const float mean = s * invn;
    const float var  = fmaxf(q * invn - mean * mean, 0.f);
    ws[WS_MEAN + (size_t)g * U + t] = mean;
    ws[WS_INV  + (size_t)g * U + t] = 1.0f / (sqrtf(var) + GN_EPS);
}

__global__ __launch_bounds__(BLK) void gn_normalize(
    const float* __restrict__ x, const float* __restrict__ gamma,
    const float* __restrict__ beta, const float* __restrict__ ws,
    float* __restrict__ out)
{
    const int c = blockIdx.x & (CH - 1);
    const int g = blockIdx.x / CH;
    const int t = threadIdx.x;
    const int f4 = t & (UF4 - 1);
    const f32x4 m  = reinterpret_cast<const f32x4*>(ws + WS_MEAN + (size_t)g * U)[f4];
    const f32x4 iv = reinterpret_cast<const f32x4*>(ws + WS_INV  + (size_t)g * U)[f4];
    const size_t base = ((size_t)g * NPG + (size_t)c * RPC) * UF4;
    const f32x4* xv = reinterpret_cast<const f32x4*>(x)     + base;
    const f32x4* gv = reinterpret_cast<const f32x4*>(gamma) + base;
    const f32x4* bv = reinterpret_cast<const f32x4*>(beta)  + base;
    f32x4*       ov = reinterpret_cast<f32x4*>(out)         + base;
#pragma unroll 4
    for (int i = 0; i < B_ITERS; ++i) {
        const int idx = i * BLK + t;
        const f32x4 v  = xv[idx];
        const f32x4 g4 = __builtin_nontemporal_load(gv + idx);
        const f32x4 b4 = __builtin_nontemporal_load(bv + idx);
        const f32x4 o  = g4 * ((v - m) * iv) + b4;
        __builtin_nontemporal_store(o, ov + idx);
    }
}

extern "C" void kernel_launch(void* const* d_in, const int* in_sizes, int n_in,
                              void* d_out, int out_size, void* d_ws, size_t ws_size,
                              hipStream_t stream) {
    const float* x     = (const float*)d_in[0];
    const float* gamma = (const float*)d_in[1];
    const float* beta  = (const float*)d_in[2];
    float* out = (float*)d_out;
    float* ws  = (float*)d_ws;
    (void)in_sizes; (void)n_in; (void)out_size; (void)ws_size;

    void* args[] = { (void*)&x, (void*)&gamma, (void*)&beta, (void*)&ws, (void*)&out };
    hipError_t e = hipLaunchCooperativeKernel((const void*)gn_fused,
                                              dim3(NBLK), dim3(BLK),
                                              args, 0, stream);
    if (e != hipSuccess) {
        // Cooperative launch unavailable -> proven 3-kernel path (round 4 behavior)
        gn_partial  <<<NBLK,       BLK, 0, stream>>>(x, ws);
        gn_finalize <<<NGRAPH,     U,   0, stream>>>(ws);
        gn_normalize<<<NBLK,       BLK, 0, stream>>>(x, gamma, beta, ws, out);
    }
}

// Round 9
// 400.477 us; speedup vs baseline: 2.0040x; 2.0040x over previous
//
#include <hip/hip_runtime.h>

#define GN_EPS 1e-5f

typedef float f32x4 __attribute__((ext_vector_type(4)));

// Problem constants (fixed by setup_inputs): N=131072, U=256, B=64
constexpr int U       = 256;                 // units (row = 1 KB = 64 lanes x 16 B)
constexpr int NPG     = 2048;                // nodes (rows) per graph
constexpr int NGRAPH  = 64;
constexpr int UF4     = U / 4;               // 64 float4 per row

constexpr int CH      = 32;                  // chunks per graph
constexpr int RPC     = NPG / CH;            // 64 rows per chunk
constexpr int BLK     = 256;                 // 4 waves
constexpr int WAVES   = BLK / 64;
constexpr int NBLK    = NGRAPH * CH;         // 2048 blocks = 8/CU
constexpr int RPW     = RPC / WAVES;         // 16 contiguous rows per wave (K1)
constexpr int B_ITERS = RPC * UF4 / BLK;     // 16 float4 per thread (K3)

// Workspace layout (floats), ~4.3 MB:
constexpr size_t WS_SUM  = 0;
constexpr size_t WS_SQ   = (size_t)NGRAPH * CH * U;
constexpr size_t WS_MEAN = WS_SQ + (size_t)NGRAPH * CH * U;
constexpr size_t WS_INV  = WS_MEAN + (size_t)NGRAPH * U;

// ---------- K1: partial column sums; each wave streams a CONTIGUOUS 16 KB ----------
__global__ __launch_bounds__(BLK) void gn_partial(
    const float* __restrict__ x, float* __restrict__ ws)
{
    const int c    = blockIdx.x & (CH - 1);
    const int g    = blockIdx.x / CH;
    const int t    = threadIdx.x;
    const int wave = t >> 6;
    const int lane = t & 63;

    // wave w owns rows [w*RPW, (w+1)*RPW) of the chunk: linear 16 KB stream,
    // thread's consecutive loads stride exactly 1 KB (one row).
    const size_t row0 = (size_t)g * NPG + (size_t)c * RPC + (size_t)wave * RPW;
    const f32x4* xr = reinterpret_cast<const f32x4*>(x) + row0 * UF4 + lane;

    // Dual accumulator pairs decouple the dependency chains.
    f32x4 s0 = (f32x4)0.f, q0 = (f32x4)0.f;
    f32x4 s1 = (f32x4)0.f, q1 = (f32x4)0.f;
#pragma unroll
    for (int i = 0; i < RPW; i += 2) {
        const f32x4 v0 = xr[(size_t)(i    ) * UF4];
        const f32x4 v1 = xr[(size_t)(i + 1) * UF4];
        s0 += v0; q0 += v0 * v0;
        s1 += v1; q1 += v1 * v1;
    }
    const f32x4 s = s0 + s1;
    const f32x4 q = q0 + q1;

    __shared__ f32x4 ssum[WAVES][64];
    __shared__ f32x4 ssq [WAVES][64];
    ssum[wave][lane] = s;
    ssq [wave][lane] = q;
    __syncthreads();

    if (t < 64) {
        f32x4 s2 = ssum[0][t];
        f32x4 q2 = ssq [0][t];
#pragma unroll
        for (int w = 1; w < WAVES; ++w) { s2 += ssum[w][t]; q2 += ssq[w][t]; }
        const size_t o = ((size_t)g * CH + c) * UF4 + t;
        reinterpret_cast<f32x4*>(ws + WS_SUM)[o] = s2;
        reinterpret_cast<f32x4*>(ws + WS_SQ )[o] = q2;
    }
}

// ---------- K2: reduce CH partials -> mean, 1/(std+eps) per (graph, unit) ----------
__global__ __launch_bounds__(U) void gn_finalize(float* __restrict__ ws)
{
    const int g = blockIdx.x;
    const int t = threadIdx.x;
    const float* psum = ws + WS_SUM + (size_t)g * CH * U + t;
    const float* psq  = ws + WS_SQ  + (size_t)g * CH * U + t;
    float s = 0.f, q = 0.f;
#pragma unroll
    for (int c = 0; c < CH; ++c) { s += psum[(size_t)c * U]; q += psq[(size_t)c * U]; }
    const float invn = 1.0f / (float)NPG;
    const float mean = s * invn;
    const float var  = fmaxf(q * invn - mean * mean, 0.f);
    ws[WS_MEAN + (size_t)g * U + t] = mean;
    ws[WS_INV  + (size_t)g * U + t] = 1.0f / (sqrtf(var) + GN_EPS);
}

// ---------- K3: normalize + affine, pure streaming, reg-resident stats ----------
// Measured at the DRAM-path ceiling (77.5 us, ~6.9 TB/s combined) — do not touch.
__global__ __launch_bounds__(BLK) void gn_normalize(
    const float* __restrict__ x, const float* __restrict__ gamma,
    const float* __restrict__ beta, const float* __restrict__ ws,
    float* __restrict__ out)
{
    const int c = blockIdx.x & (CH - 1);
    const int g = blockIdx.x / CH;
    const int t = threadIdx.x;

    // BLK % 64 == 0 => thread t always touches float4-column (t & 63):
    // stats are loop-invariant registers, no LDS, no barrier.
    const int f4 = t & (UF4 - 1);
    const f32x4 m  = reinterpret_cast<const f32x4*>(ws + WS_MEAN + (size_t)g * U)[f4];
    const f32x4 iv = reinterpret_cast<const f32x4*>(ws + WS_INV  + (size_t)g * U)[f4];

    const size_t base = ((size_t)g * NPG + (size_t)c * RPC) * UF4;
    const f32x4* xv = reinterpret_cast<const f32x4*>(x)     + base;
    const f32x4* gv = reinterpret_cast<const f32x4*>(gamma) + base;
    const f32x4* bv = reinterpret_cast<const f32x4*>(beta)  + base;
    f32x4*       ov = reinterpret_cast<f32x4*>(out)         + base;

#pragma unroll 4
    for (int i = 0; i < B_ITERS; ++i) {
        const int idx = i * BLK + t;
        const f32x4 v  = xv[idx];                               // L3-hot from K1
        const f32x4 g4 = __builtin_nontemporal_load(gv + idx);  // single-use streams
        const f32x4 b4 = __builtin_nontemporal_load(bv + idx);
        const f32x4 o  = g4 * ((v - m) * iv) + b4;
        __builtin_nontemporal_store(o, ov + idx);               // don't evict reads
    }
}

extern "C" void kernel_launch(void* const* d_in, const int* in_sizes, int n_in,
                              void* d_out, int out_size, void* d_ws, size_t ws_size,
                              hipStream_t stream) {
    const float* x     = (const float*)d_in[0];
    const float* gamma = (const float*)d_in[1];
    const float* beta  = (const float*)d_in[2];
    float* out = (float*)d_out;
    float* ws  = (float*)d_ws;
    (void)in_sizes; (void)n_in; (void)out_size; (void)ws_size;

    gn_partial  <<<NBLK,   BLK, 0, stream>>>(x, ws);
    gn_finalize <<<NGRAPH, U,   0, stream>>>(ws);
    gn_normalize<<<NBLK,   BLK, 0, stream>>>(x, gamma, beta, ws, out);
}